// Round 4
// baseline (242.896 us; speedup 1.0000x reference)
//
#include <hip/hip_runtime.h>
#include <hip/hip_bf16.h>

using u16 = unsigned short;
using u32 = unsigned int;
typedef float f32x4 __attribute__((ext_vector_type(4)));
typedef __bf16 bf16x8 __attribute__((ext_vector_type(8)));

// ---- helpers ----------------------------------------------------------------
static __device__ __forceinline__ float bflo(u32 u) { return __uint_as_float(u << 16); }
static __device__ __forceinline__ float bfhi(u32 u) { return __uint_as_float(u & 0xffff0000u); }

static __device__ __forceinline__ u32 pack2(float a, float b) {
  __hip_bfloat16 ha = __float2bfloat16(a);
  __hip_bfloat16 hb = __float2bfloat16(b);
  u16 ra, rb;
  __builtin_memcpy(&ra, &ha, 2);
  __builtin_memcpy(&rb, &hb, 2);
  return (u32)ra | ((u32)rb << 16);
}

static __device__ __forceinline__ u16 f2bf(float f) {
  u32 u = __float_as_uint(f);
  u32 r = (u + 0x7fffu + ((u >> 16) & 1u)) >> 16;
  return (u16)r;
}

static __device__ __forceinline__ bf16x8 as_bf(uint4 v) {
  bf16x8 r;
  __builtin_memcpy(&r, &v, 16);
  return r;
}

// truncating pack of two blended f32 -> bf16x2, single v_perm_b32
static __device__ __forceinline__ u32 packtrunc(float lo, float hi) {
  return __builtin_amdgcn_perm(__float_as_uint(hi), __float_as_uint(lo), 0x07060302u);
}

// 4-corner bilinear blend of 8 bf16 channels -> bf16x8 fragment (as uint4)
static __device__ __forceinline__ uint4 blend4(uint4 a, uint4 b, uint4 c, uint4 d,
                                               float w00, float w01, float w10, float w11) {
  uint4 r;
#pragma unroll
  for (int j = 0; j < 4; j++) {
    u32 u0 = (&a.x)[j], u1 = (&b.x)[j], u2 = (&c.x)[j], u3 = (&d.x)[j];
    float lo = w00 * bflo(u0) + w01 * bflo(u1) + w10 * bflo(u2) + w11 * bflo(u3);
    float hi = w00 * bfhi(u0) + w01 * bfhi(u1) + w10 * bfhi(u2) + w11 * bfhi(u3);
    (&r.x)[j] = packtrunc(lo, hi);
  }
  return r;
}

// ---- kernel 1: x [B,C,H,W] f32 -> xT [B,H,W,C] bf16 -------------------------
__global__ __launch_bounds__(256) void transpose_k(const float* __restrict__ x,
                                                   u16* __restrict__ xT) {
  const int bid = blockIdx.x;
  const int b = bid >> 6, y = bid & 63;
  const int t = threadIdx.x;
  const int cg = t >> 4;
  const int w16 = t & 15;
  const float* xp = x + ((size_t)(b * 128) * 64 + y) * 64;
  u16* op = xT + ((size_t)(b * 64 + y) * 64) * 128;
#pragma unroll
  for (int pass = 0; pass < 4; pass++) {
    int w = pass * 16 + w16;
    u32 rr[4];
#pragma unroll
    for (int jj = 0; jj < 4; jj++) {
      float a = xp[(cg * 8 + 2 * jj) * 4096 + w];
      float c = xp[(cg * 8 + 2 * jj + 1) * 4096 + w];
      rr[jj] = pack2(a, c);
    }
    uint4 r;
    r.x = rr[0]; r.y = rr[1]; r.z = rr[2]; r.w = rr[3];
    *(uint4*)(op + w * 128 + cg * 8) = r;
  }
}

// ---- kernel 2: weff in MFMA-A-fragment layout --------------------------------
// element index = ((ks*6 + nt)*64 + lane)*8 + j
//   n (=o) = nt*16 + (lane&15);  kc = (lane>>4)*8 + j
// ks: br = ks>=36, ksb = ks-36*br, tap = ksb>>2, chunk = ksb&3, c = chunk*32+kc
__global__ __launch_bounds__(256) void weff_k(const float* __restrict__ w0,
                                              const float* __restrict__ w1,
                                              const float* __restrict__ wf,
                                              u16* __restrict__ weffg) {
  const int idx = blockIdx.x * 256 + threadIdx.x;  // 221184 total
  const int j = idx & 7;
  const int l = (idx >> 3) & 63;
  const int rest = idx >> 9;       // ks*6 + nt, 0..431
  const int nt = rest % 6;
  const int ks = rest / 6;
  const int n = nt * 16 + (l & 15);
  const int kc = (l >> 4) * 8 + j;
  const int br = ks >= 36 ? 1 : 0;
  const int ksb = ks - br * 36;
  const int tap = ksb >> 2, chunk = ksb & 3;
  const int c = chunk * 32 + kc;
  float acc = 0.f;
  if (n < 84) {
    const float* w = br ? w1 : w0;
    const float* wfp = wf + n * 168 + br * 84;
    const float* wp = w + c * 9 + tap;   // stride per oc = 128*9 = 1152
#pragma unroll 4
    for (int oc = 0; oc < 84; oc++) acc += wfp[oc] * wp[oc * 1152];
  }
  weffg[idx] = f2bf(acc);
}

// ---- kernel 3: fused deform-sample + GEMM ------------------------------------
// 1024 blocks = (b:8 -> XCD) x (h:64) x (half:2). 4 waves = (br:2, cp:2).
// Wave: 32 px x 96 out x K=576 (9 taps x 2 chunks of 32ch).
// Pipeline: tap t+1's 16 corner gathers issued at end of tap t (latency hidden
// under next tap's blends+MFMAs); dm prefetched 2 taps ahead; weff c1 loaded
// under MFMA c0. No barriers in main loop.
__global__ __launch_bounds__(256, 3) void deform_main(
    const u16* __restrict__ xT, const u16* __restrict__ weffg,
    const float* __restrict__ dm0, const float* __restrict__ dm1,
    const float* __restrict__ bias, float* __restrict__ out) {
  __shared__ f32x4 red[2][6][2][64];   // 24 KiB

  const int t = threadIdx.x;
  const int wv = t >> 6, lane = t & 63;
  const int br = wv >> 1, cp = wv & 1;
  const int lrow = lane & 15, lg = lane >> 4;
  const int blk = blockIdx.x;
  const int b = blk & 7;
  const int rem = blk >> 3;
  const int h = rem & 63;
  const int half = rem >> 6;           // 0..1
  const int px0 = half * 32;

  const u16* xb = xT + (size_t)b * 524288;
  const float* dmb = (br ? dm1 : dm0) + (size_t)b * 73728 + h * 64 + px0 + lrow;
  const u16* wbase = weffg + (size_t)(br * 36 + cp * 2) * 3072 + lane * 8;
  const int cb = cp * 64 + lg * 8;     // channel base (u16 elems) for this lane

  f32x4 acc[6][2];
#pragma unroll
  for (int i = 0; i < 6; i++)
#pragma unroll
    for (int f = 0; f < 2; f++) acc[i][f] = f32x4{0.f, 0.f, 0.f, 0.f};

  float w00a[2], w01a[2], w10a[2], w11a[2];
  int r0a[2], r1a[2], xo0a[2], xo1a[2];
  uint4 q[16];   // corner gathers in flight: [chunk][frag][corner]

  auto tapstate = [&](int f, int ty, int tx, float dy, float dx) {
    float pyf = (float)(h + ty - 1) + dy;
    float pxf = (float)(px0 + f * 16 + lrow + tx - 1) + dx;
    float y0f = floorf(pyf), x0f = floorf(pxf);
    int y0 = (int)y0f, x0 = (int)x0f;
    float wy1 = pyf - y0f, wx1 = pxf - x0f;
    float wy0 = 1.f - wy1, wx0 = 1.f - wx1;
    int y1 = y0 + 1, x1 = x0 + 1;
    wy0 *= ((u32)y0 < 64u) ? 1.f : 0.f;
    wy1 *= ((u32)y1 < 64u) ? 1.f : 0.f;
    wx0 *= ((u32)x0 < 64u) ? 1.f : 0.f;
    wx1 *= ((u32)x1 < 64u) ? 1.f : 0.f;
    w00a[f] = wy0 * wx0; w01a[f] = wy0 * wx1;
    w10a[f] = wy1 * wx0; w11a[f] = wy1 * wx1;
    int y0c = min(63, max(0, y0)), y1c = min(63, max(0, y1));
    int x0c = min(63, max(0, x0)), x1c = min(63, max(0, x1));
    r0a[f] = y0c * 8192 + cb; r1a[f] = y1c * 8192 + cb;
    xo0a[f] = x0c * 128; xo1a[f] = x1c * 128;
  };

  auto issue = [&]() {
#pragma unroll
    for (int c = 0; c < 2; c++)
#pragma unroll
      for (int f = 0; f < 2; f++) {
        const u16* p0 = xb + r0a[f] + c * 32;
        const u16* p1 = xb + r1a[f] + c * 32;
        q[c * 8 + f * 4 + 0] = *(const uint4*)(p0 + xo0a[f]);
        q[c * 8 + f * 4 + 1] = *(const uint4*)(p0 + xo1a[f]);
        q[c * 8 + f * 4 + 2] = *(const uint4*)(p1 + xo0a[f]);
        q[c * 8 + f * 4 + 3] = *(const uint4*)(p1 + xo1a[f]);
      }
  };

  // prologue: tap0 state + gathers; dm for tap1 in flight
  float dyN0, dxN0, dyN1, dxN1;
  {
    float dy0 = dmb[0], dx0 = dmb[4096];
    float dy1 = dmb[16], dx1 = dmb[4096 + 16];
    tapstate(0, 0, 0, dy0, dx0);
    tapstate(1, 0, 0, dy1, dx1);
  }
  dyN0 = dmb[2 * 4096]; dxN0 = dmb[3 * 4096];
  dyN1 = dmb[2 * 4096 + 16]; dxN1 = dmb[3 * 4096 + 16];
  issue();

#pragma unroll 1
  for (int tap = 0; tap < 9; tap++) {
    const u16* wp = wbase + (size_t)tap * 12288;
    // weff chunk 0
    uint4 wq0 = *(const uint4*)(wp);
    uint4 wq1 = *(const uint4*)(wp + 512);
    uint4 wq2 = *(const uint4*)(wp + 1024);
    uint4 wq3 = *(const uint4*)(wp + 1536);
    uint4 wq4 = *(const uint4*)(wp + 2048);
    uint4 wq5 = *(const uint4*)(wp + 2560);

    // blend chunk 0 (corners issued last tap -> latency already covered)
    uint4 a00 = blend4(q[0], q[1], q[2], q[3], w00a[0], w01a[0], w10a[0], w11a[0]);
    uint4 a01 = blend4(q[4], q[5], q[6], q[7], w00a[1], w01a[1], w10a[1], w11a[1]);

    bf16x8 af0 = as_bf(a00), af1 = as_bf(a01);
    __builtin_amdgcn_s_setprio(1);
    acc[0][0] = __builtin_amdgcn_mfma_f32_16x16x32_bf16(as_bf(wq0), af0, acc[0][0], 0, 0, 0);
    acc[1][0] = __builtin_amdgcn_mfma_f32_16x16x32_bf16(as_bf(wq1), af0, acc[1][0], 0, 0, 0);
    acc[2][0] = __builtin_amdgcn_mfma_f32_16x16x32_bf16(as_bf(wq2), af0, acc[2][0], 0, 0, 0);
    acc[3][0] = __builtin_amdgcn_mfma_f32_16x16x32_bf16(as_bf(wq3), af0, acc[3][0], 0, 0, 0);
    acc[4][0] = __builtin_amdgcn_mfma_f32_16x16x32_bf16(as_bf(wq4), af0, acc[4][0], 0, 0, 0);
    acc[5][0] = __builtin_amdgcn_mfma_f32_16x16x32_bf16(as_bf(wq5), af0, acc[5][0], 0, 0, 0);
    acc[0][1] = __builtin_amdgcn_mfma_f32_16x16x32_bf16(as_bf(wq0), af1, acc[0][1], 0, 0, 0);
    acc[1][1] = __builtin_amdgcn_mfma_f32_16x16x32_bf16(as_bf(wq1), af1, acc[1][1], 0, 0, 0);
    acc[2][1] = __builtin_amdgcn_mfma_f32_16x16x32_bf16(as_bf(wq2), af1, acc[2][1], 0, 0, 0);
    acc[3][1] = __builtin_amdgcn_mfma_f32_16x16x32_bf16(as_bf(wq3), af1, acc[3][1], 0, 0, 0);
    acc[4][1] = __builtin_amdgcn_mfma_f32_16x16x32_bf16(as_bf(wq4), af1, acc[4][1], 0, 0, 0);
    acc[5][1] = __builtin_amdgcn_mfma_f32_16x16x32_bf16(as_bf(wq5), af1, acc[5][1], 0, 0, 0);
    __builtin_amdgcn_s_setprio(0);

    // weff chunk 1 (L1-hot, covered by blends below)
    uint4 wr0 = *(const uint4*)(wp + 3072);
    uint4 wr1 = *(const uint4*)(wp + 3584);
    uint4 wr2 = *(const uint4*)(wp + 4096);
    uint4 wr3 = *(const uint4*)(wp + 4608);
    uint4 wr4 = *(const uint4*)(wp + 5120);
    uint4 wr5 = *(const uint4*)(wp + 5632);

    // blend chunk 1
    uint4 a10 = blend4(q[8], q[9], q[10], q[11], w00a[0], w01a[0], w10a[0], w11a[0]);
    uint4 a11 = blend4(q[12], q[13], q[14], q[15], w00a[1], w01a[1], w10a[1], w11a[1]);

    // next tap: state + issue gathers (in flight under MFMA c1 and next blends)
    if (tap < 8) {
      int tn = tap + 1;
      int ty = (tn * 11) >> 5;     // tn/3
      int tx = tn - ty * 3;
      tapstate(0, ty, tx, dyN0, dxN0);
      tapstate(1, ty, tx, dyN1, dxN1);
      issue();
      if (tap < 7) {
        dyN0 = dmb[(2 * tap + 4) * 4096]; dxN0 = dmb[(2 * tap + 5) * 4096];
        dyN1 = dmb[(2 * tap + 4) * 4096 + 16]; dxN1 = dmb[(2 * tap + 5) * 4096 + 16];
      }
    }

    bf16x8 af2 = as_bf(a10), af3 = as_bf(a11);
    __builtin_amdgcn_s_setprio(1);
    acc[0][0] = __builtin_amdgcn_mfma_f32_16x16x32_bf16(as_bf(wr0), af2, acc[0][0], 0, 0, 0);
    acc[1][0] = __builtin_amdgcn_mfma_f32_16x16x32_bf16(as_bf(wr1), af2, acc[1][0], 0, 0, 0);
    acc[2][0] = __builtin_amdgcn_mfma_f32_16x16x32_bf16(as_bf(wr2), af2, acc[2][0], 0, 0, 0);
    acc[3][0] = __builtin_amdgcn_mfma_f32_16x16x32_bf16(as_bf(wr3), af2, acc[3][0], 0, 0, 0);
    acc[4][0] = __builtin_amdgcn_mfma_f32_16x16x32_bf16(as_bf(wr4), af2, acc[4][0], 0, 0, 0);
    acc[5][0] = __builtin_amdgcn_mfma_f32_16x16x32_bf16(as_bf(wr5), af2, acc[5][0], 0, 0, 0);
    acc[0][1] = __builtin_amdgcn_mfma_f32_16x16x32_bf16(as_bf(wr0), af3, acc[0][1], 0, 0, 0);
    acc[1][1] = __builtin_amdgcn_mfma_f32_16x16x32_bf16(as_bf(wr1), af3, acc[1][1], 0, 0, 0);
    acc[2][1] = __builtin_amdgcn_mfma_f32_16x16x32_bf16(as_bf(wr2), af3, acc[2][1], 0, 0, 0);
    acc[3][1] = __builtin_amdgcn_mfma_f32_16x16x32_bf16(as_bf(wr3), af3, acc[3][1], 0, 0, 0);
    acc[4][1] = __builtin_amdgcn_mfma_f32_16x16x32_bf16(as_bf(wr4), af3, acc[4][1], 0, 0, 0);
    acc[5][1] = __builtin_amdgcn_mfma_f32_16x16x32_bf16(as_bf(wr5), af3, acc[5][1], 0, 0, 0);
    __builtin_amdgcn_s_setprio(0);
  }

  // ---- reduce 4 K-partials, add bias, store ----
  if (wv >= 2) {
#pragma unroll
    for (int nt = 0; nt < 6; nt++)
#pragma unroll
      for (int f = 0; f < 2; f++) red[wv - 2][nt][f][lane] = acc[nt][f];
  }
  __syncthreads();
  if (wv < 2) {
#pragma unroll
    for (int nt = 0; nt < 6; nt++)
#pragma unroll
      for (int f = 0; f < 2; f++) {
        f32x4 v = red[wv][nt][f][lane];
#pragma unroll
        for (int j = 0; j < 4; j++) acc[nt][f][j] += v[j];
      }
  }
  if (wv == 1) {
#pragma unroll
    for (int nt = 0; nt < 6; nt++)
#pragma unroll
      for (int f = 0; f < 2; f++) red[1][nt][f][lane] = acc[nt][f];
  }
  __syncthreads();
  if (wv == 0) {
    float* op = out + ((size_t)b * 84 * 64 + h) * 64 + px0;
#pragma unroll
    for (int nt = 0; nt < 6; nt++)
#pragma unroll
      for (int f = 0; f < 2; f++) {
        f32x4 v = red[1][nt][f][lane];
#pragma unroll
        for (int j = 0; j < 4; j++) acc[nt][f][j] += v[j];
      }
#pragma unroll
    for (int nt = 0; nt < 6; nt++)
#pragma unroll
      for (int j = 0; j < 4; j++) {
        int o = nt * 16 + lg * 4 + j;
        if (o < 84) {
          float bv = bias[o];
#pragma unroll
          for (int f = 0; f < 2; f++)
            op[(size_t)o * 4096 + f * 16 + lrow] = acc[nt][f][j] + bv;
        }
      }
  }
}

// ---- launch -----------------------------------------------------------------
extern "C" void kernel_launch(void* const* d_in, const int* in_sizes, int n_in,
                              void* d_out, int out_size, void* d_ws, size_t ws_size,
                              hipStream_t stream) {
  const float* x   = (const float*)d_in[0];
  const float* dm0 = (const float*)d_in[1];
  const float* dm1 = (const float*)d_in[2];
  const float* w0  = (const float*)d_in[3];
  const float* w1  = (const float*)d_in[4];
  const float* wf  = (const float*)d_in[5];
  const float* bf  = (const float*)d_in[6];
  float* out = (float*)d_out;

  u16* xT = (u16*)d_ws;                                               // 8 MiB
  u16* weffg = (u16*)((char*)d_ws + (size_t)8 * 64 * 64 * 128 * 2);   // 432 KiB

  transpose_k<<<512, 256, 0, stream>>>(x, xT);
  weff_k<<<864, 256, 0, stream>>>(w0, w1, wf, weffg);
  deform_main<<<1024, 256, 0, stream>>>(xT, weffg, dm0, dm1, bf, out);
}

// Round 5
// 105.262 us; speedup vs baseline: 2.3075x; 2.3075x over previous
//
#include <hip/hip_runtime.h>
#include <hip/hip_bf16.h>

using u16 = unsigned short;
using u32 = unsigned int;
typedef float f32x4 __attribute__((ext_vector_type(4)));
typedef float f32x2 __attribute__((ext_vector_type(2)));
typedef __bf16 bf16x8 __attribute__((ext_vector_type(8)));

// ---- helpers ----------------------------------------------------------------
static __device__ __forceinline__ float bflo(u32 u) { return __uint_as_float(u << 16); }
static __device__ __forceinline__ float bfhi(u32 u) { return __uint_as_float(u & 0xffff0000u); }

static __device__ __forceinline__ u32 pack2(float a, float b) {
  __hip_bfloat16 ha = __float2bfloat16(a);
  __hip_bfloat16 hb = __float2bfloat16(b);
  u16 ra, rb;
  __builtin_memcpy(&ra, &ha, 2);
  __builtin_memcpy(&rb, &hb, 2);
  return (u32)ra | ((u32)rb << 16);
}

static __device__ __forceinline__ u16 f2bf(float f) {
  u32 u = __float_as_uint(f);
  u32 r = (u + 0x7fffu + ((u >> 16) & 1u)) >> 16;
  return (u16)r;
}

static __device__ __forceinline__ bf16x8 as_bf(uint4 v) {
  bf16x8 r;
  __builtin_memcpy(&r, &v, 16);
  return r;
}

// truncating pack of two blended f32 -> bf16x2, single v_perm_b32
static __device__ __forceinline__ u32 packtrunc(float lo, float hi) {
  return __builtin_amdgcn_perm(__float_as_uint(hi), __float_as_uint(lo), 0x07060302u);
}

static __device__ __forceinline__ f32x2 unpk(u32 u) {
  f32x2 r;
  r.x = bflo(u);
  r.y = bfhi(u);
  return r;
}

// 4-corner bilinear blend of 8 bf16 channels -> bf16x8 fragment (as uint4)
// float2 arithmetic to give the compiler a shot at v_pk_fma_f32
static __device__ __forceinline__ uint4 blend4(uint4 a, uint4 b, uint4 c, uint4 d,
                                               float w00, float w01, float w10, float w11) {
  uint4 r;
#pragma unroll
  for (int j = 0; j < 4; j++) {
    f32x2 v = unpk((&a.x)[j]) * w00;
    v += unpk((&b.x)[j]) * w01;
    v += unpk((&c.x)[j]) * w10;
    v += unpk((&d.x)[j]) * w11;
    (&r.x)[j] = packtrunc(v.x, v.y);
  }
  return r;
}

// ---- kernel 1: x [B,C,H,W] f32 -> xT [B,H,W,C] bf16 -------------------------
__global__ __launch_bounds__(256) void transpose_k(const float* __restrict__ x,
                                                   u16* __restrict__ xT) {
  const int bid = blockIdx.x;
  const int b = bid >> 6, y = bid & 63;
  const int t = threadIdx.x;
  const int cg = t >> 4;
  const int w16 = t & 15;
  const float* xp = x + ((size_t)(b * 128) * 64 + y) * 64;
  u16* op = xT + ((size_t)(b * 64 + y) * 64) * 128;
#pragma unroll
  for (int pass = 0; pass < 4; pass++) {
    int w = pass * 16 + w16;
    u32 rr[4];
#pragma unroll
    for (int jj = 0; jj < 4; jj++) {
      float a = xp[(cg * 8 + 2 * jj) * 4096 + w];
      float c = xp[(cg * 8 + 2 * jj + 1) * 4096 + w];
      rr[jj] = pack2(a, c);
    }
    uint4 r;
    r.x = rr[0]; r.y = rr[1]; r.z = rr[2]; r.w = rr[3];
    *(uint4*)(op + w * 128 + cg * 8) = r;
  }
}

// ---- kernel 2: weff in MFMA-A-fragment layout --------------------------------
// element index = ((ks*6 + nt)*64 + lane)*8 + j
//   n (=o) = nt*16 + (lane&15);  kc = (lane>>4)*8 + j
// ks: br = ks>=36, ksb = ks-36*br, tap = ksb>>2, chunk = ksb&3, c = chunk*32+kc
__global__ __launch_bounds__(256) void weff_k(const float* __restrict__ w0,
                                              const float* __restrict__ w1,
                                              const float* __restrict__ wf,
                                              u16* __restrict__ weffg) {
  const int idx = blockIdx.x * 256 + threadIdx.x;  // 221184 total
  const int j = idx & 7;
  const int l = (idx >> 3) & 63;
  const int rest = idx >> 9;       // ks*6 + nt, 0..431
  const int nt = rest % 6;
  const int ks = rest / 6;
  const int n = nt * 16 + (l & 15);
  const int kc = (l >> 4) * 8 + j;
  const int br = ks >= 36 ? 1 : 0;
  const int ksb = ks - br * 36;
  const int tap = ksb >> 2, chunk = ksb & 3;
  const int c = chunk * 32 + kc;
  float acc = 0.f;
  if (n < 84) {
    const float* w = br ? w1 : w0;
    const float* wfp = wf + n * 168 + br * 84;
    const float* wp = w + c * 9 + tap;   // stride per oc = 128*9 = 1152
#pragma unroll 4
    for (int oc = 0; oc < 84; oc++) acc += wfp[oc] * wp[oc * 1152];
  }
  weffg[idx] = f2bf(acc);
}

// ---- kernel 3: fused deform-sample + GEMM, one-phase-ahead gather pipeline ---
// 512 blocks = (b:8 -> XCD-pinned L2) x (h:64). 4 waves = (br:2, cp:2).
// Wave: 64 px x 96 out x K=576 as 18 phases (9 taps x 2 chunks of 32 ch).
// Phase: weff(6 loads) | blend qa | 12 MFMA | blend qb | issue qa+qb for NEXT
// phase (tapstate recomputed in-place at tap boundary) | 12 MFMA.
// Every gather has ~1 phase (>=200 cyc of MFMA+blend) of latency cover.
// NOTE launch_bounds: on this toolchain (256,w) caps VGPR at ~512/(2w);
// (256,3) caused an 84-VGPR cap -> scratch spill -> 464MB WRITE_SIZE (round 4).
// (256,1) -> cap 256, fits the ~230-reg working set; grid gives 2 blocks/CU.
__global__ __launch_bounds__(256, 1) void deform_main(
    const u16* __restrict__ xT, const u16* __restrict__ weffg,
    const float* __restrict__ dm0, const float* __restrict__ dm1,
    const float* __restrict__ bias, float* __restrict__ out) {
  __shared__ f32x4 red[2][6][4][64];   // 48 KiB

  const int t = threadIdx.x;
  const int wv = t >> 6, lane = t & 63;
  const int br = wv >> 1, cp = wv & 1;
  const int lrow = lane & 15, lg = lane >> 4;
  const int blk = blockIdx.x;
  const int b = blk & 7, h = blk >> 3;

  const u16* xb = xT + (size_t)b * 524288;
  const float* dmb = (br ? dm1 : dm0) + (size_t)b * 73728 + h * 64 + lrow;
  const u16* wbase = weffg + (size_t)(br * 36 + cp * 2) * 3072 + lane * 8;
  const int cb = cp * 64 + lg * 8;     // channel base (u16 elems) for this lane

  f32x4 acc[6][4];
#pragma unroll
  for (int i = 0; i < 6; i++)
#pragma unroll
    for (int f = 0; f < 4; f++) acc[i][f] = f32x4{0.f, 0.f, 0.f, 0.f};

  float w00a[4], w01a[4], w10a[4], w11a[4];
  int r0a[4], r1a[4], xo0a[4], xo1a[4];
  float dyN[4], dxN[4];
  uint4 qa[8], qb[8];    // frags 0,1 / frags 2,3 — 4 corners each, in flight

  auto tapstate = [&](int f, int ty, int tx, float dy, float dx) {
    float pyf = (float)(h + ty - 1) + dy;
    float pxf = (float)(f * 16 + lrow + tx - 1) + dx;
    float y0f = floorf(pyf), x0f = floorf(pxf);
    int y0 = (int)y0f, x0 = (int)x0f;
    float wy1 = pyf - y0f, wx1 = pxf - x0f;
    float wy0 = 1.f - wy1, wx0 = 1.f - wx1;
    int y1 = y0 + 1, x1 = x0 + 1;
    wy0 *= ((u32)y0 < 64u) ? 1.f : 0.f;
    wy1 *= ((u32)y1 < 64u) ? 1.f : 0.f;
    wx0 *= ((u32)x0 < 64u) ? 1.f : 0.f;
    wx1 *= ((u32)x1 < 64u) ? 1.f : 0.f;
    w00a[f] = wy0 * wx0; w01a[f] = wy0 * wx1;
    w10a[f] = wy1 * wx0; w11a[f] = wy1 * wx1;
    int y0c = min(63, max(0, y0)), y1c = min(63, max(0, y1));
    int x0c = min(63, max(0, x0)), x1c = min(63, max(0, x1));
    r0a[f] = y0c * 8192 + cb; r1a[f] = y1c * 8192 + cb;
    xo0a[f] = x0c * 128; xo1a[f] = x1c * 128;
  };

  auto issueA = [&](int co) {
#pragma unroll
    for (int f = 0; f < 2; f++) {
      const u16* p0 = xb + r0a[f] + co;
      const u16* p1 = xb + r1a[f] + co;
      qa[f * 4 + 0] = *(const uint4*)(p0 + xo0a[f]);
      qa[f * 4 + 1] = *(const uint4*)(p0 + xo1a[f]);
      qa[f * 4 + 2] = *(const uint4*)(p1 + xo0a[f]);
      qa[f * 4 + 3] = *(const uint4*)(p1 + xo1a[f]);
    }
  };
  auto issueB = [&](int co) {
#pragma unroll
    for (int f = 0; f < 2; f++) {
      int g = f + 2;
      const u16* p0 = xb + r0a[g] + co;
      const u16* p1 = xb + r1a[g] + co;
      qb[f * 4 + 0] = *(const uint4*)(p0 + xo0a[g]);
      qb[f * 4 + 1] = *(const uint4*)(p0 + xo1a[g]);
      qb[f * 4 + 2] = *(const uint4*)(p1 + xo0a[g]);
      qb[f * 4 + 3] = *(const uint4*)(p1 + xo1a[g]);
    }
  };

  // ---- prologue: tap 0 state, issue phase-0 gathers, prefetch dm(tap1) ----
#pragma unroll
  for (int f = 0; f < 4; f++) {
    dyN[f] = dmb[f * 16];
    dxN[f] = dmb[4096 + f * 16];
  }
#pragma unroll
  for (int f = 0; f < 4; f++) tapstate(f, 0, 0, dyN[f], dxN[f]);
  issueA(0);
  issueB(0);
#pragma unroll
  for (int f = 0; f < 4; f++) {
    dyN[f] = dmb[2 * 4096 + f * 16];
    dxN[f] = dmb[3 * 4096 + f * 16];
  }

#pragma unroll 1
  for (int tap = 0; tap < 9; tap++) {
#pragma unroll
    for (int c = 0; c < 2; c++) {
      const u16* wp = wbase + (size_t)(tap * 4 + c) * 3072;
      uint4 wq0 = *(const uint4*)(wp);
      uint4 wq1 = *(const uint4*)(wp + 512);
      uint4 wq2 = *(const uint4*)(wp + 1024);
      uint4 wq3 = *(const uint4*)(wp + 1536);
      uint4 wq4 = *(const uint4*)(wp + 2048);
      uint4 wq5 = *(const uint4*)(wp + 2560);

      // blend frags 0,1 (gathers issued one phase ago)
      uint4 a0 = blend4(qa[0], qa[1], qa[2], qa[3], w00a[0], w01a[0], w10a[0], w11a[0]);
      uint4 a1 = blend4(qa[4], qa[5], qa[6], qa[7], w00a[1], w01a[1], w10a[1], w11a[1]);

      bf16x8 af0 = as_bf(a0), af1 = as_bf(a1);
      __builtin_amdgcn_s_setprio(1);
      acc[0][0] = __builtin_amdgcn_mfma_f32_16x16x32_bf16(as_bf(wq0), af0, acc[0][0], 0, 0, 0);
      acc[1][0] = __builtin_amdgcn_mfma_f32_16x16x32_bf16(as_bf(wq1), af0, acc[1][0], 0, 0, 0);
      acc[2][0] = __builtin_amdgcn_mfma_f32_16x16x32_bf16(as_bf(wq2), af0, acc[2][0], 0, 0, 0);
      acc[3][0] = __builtin_amdgcn_mfma_f32_16x16x32_bf16(as_bf(wq3), af0, acc[3][0], 0, 0, 0);
      acc[4][0] = __builtin_amdgcn_mfma_f32_16x16x32_bf16(as_bf(wq4), af0, acc[4][0], 0, 0, 0);
      acc[5][0] = __builtin_amdgcn_mfma_f32_16x16x32_bf16(as_bf(wq5), af0, acc[5][0], 0, 0, 0);
      acc[0][1] = __builtin_amdgcn_mfma_f32_16x16x32_bf16(as_bf(wq0), af1, acc[0][1], 0, 0, 0);
      acc[1][1] = __builtin_amdgcn_mfma_f32_16x16x32_bf16(as_bf(wq1), af1, acc[1][1], 0, 0, 0);
      acc[2][1] = __builtin_amdgcn_mfma_f32_16x16x32_bf16(as_bf(wq2), af1, acc[2][1], 0, 0, 0);
      acc[3][1] = __builtin_amdgcn_mfma_f32_16x16x32_bf16(as_bf(wq3), af1, acc[3][1], 0, 0, 0);
      acc[4][1] = __builtin_amdgcn_mfma_f32_16x16x32_bf16(as_bf(wq4), af1, acc[4][1], 0, 0, 0);
      acc[5][1] = __builtin_amdgcn_mfma_f32_16x16x32_bf16(as_bf(wq5), af1, acc[5][1], 0, 0, 0);
      __builtin_amdgcn_s_setprio(0);

      // blend frags 2,3
      uint4 a2 = blend4(qb[0], qb[1], qb[2], qb[3], w00a[2], w01a[2], w10a[2], w11a[2]);
      uint4 a3 = blend4(qb[4], qb[5], qb[6], qb[7], w00a[3], w01a[3], w10a[3], w11a[3]);

      // issue next phase's gathers (qa/qb now dead -> reuse in place)
      if (c == 0) {
        issueA(32);
        issueB(32);
        if (tap < 8) {
#pragma unroll
          for (int f = 0; f < 4; f++) {
            dyN[f] = dmb[(2 * tap + 2) * 4096 + f * 16];
            dxN[f] = dmb[(2 * tap + 3) * 4096 + f * 16];
          }
        }
      } else if (tap < 8) {
        int tn = tap + 1;
        int ty = (tn * 11) >> 5;     // tn/3
        int tx = tn - ty * 3;
#pragma unroll
        for (int f = 0; f < 4; f++) tapstate(f, ty, tx, dyN[f], dxN[f]);
        issueA(0);
        issueB(0);
      }

      bf16x8 af2 = as_bf(a2), af3 = as_bf(a3);
      __builtin_amdgcn_s_setprio(1);
      acc[0][2] = __builtin_amdgcn_mfma_f32_16x16x32_bf16(as_bf(wq0), af2, acc[0][2], 0, 0, 0);
      acc[1][2] = __builtin_amdgcn_mfma_f32_16x16x32_bf16(as_bf(wq1), af2, acc[1][2], 0, 0, 0);
      acc[2][2] = __builtin_amdgcn_mfma_f32_16x16x32_bf16(as_bf(wq2), af2, acc[2][2], 0, 0, 0);
      acc[3][2] = __builtin_amdgcn_mfma_f32_16x16x32_bf16(as_bf(wq3), af2, acc[3][2], 0, 0, 0);
      acc[4][2] = __builtin_amdgcn_mfma_f32_16x16x32_bf16(as_bf(wq4), af2, acc[4][2], 0, 0, 0);
      acc[5][2] = __builtin_amdgcn_mfma_f32_16x16x32_bf16(as_bf(wq5), af2, acc[5][2], 0, 0, 0);
      acc[0][3] = __builtin_amdgcn_mfma_f32_16x16x32_bf16(as_bf(wq0), af3, acc[0][3], 0, 0, 0);
      acc[1][3] = __builtin_amdgcn_mfma_f32_16x16x32_bf16(as_bf(wq1), af3, acc[1][3], 0, 0, 0);
      acc[2][3] = __builtin_amdgcn_mfma_f32_16x16x32_bf16(as_bf(wq2), af3, acc[2][3], 0, 0, 0);
      acc[3][3] = __builtin_amdgcn_mfma_f32_16x16x32_bf16(as_bf(wq3), af3, acc[3][3], 0, 0, 0);
      acc[4][3] = __builtin_amdgcn_mfma_f32_16x16x32_bf16(as_bf(wq4), af3, acc[4][3], 0, 0, 0);
      acc[5][3] = __builtin_amdgcn_mfma_f32_16x16x32_bf16(as_bf(wq5), af3, acc[5][3], 0, 0, 0);
      __builtin_amdgcn_s_setprio(0);
    }
  }

  // ---- reduce the 4 K-partials across waves, then store ----
  if (wv >= 2) {
#pragma unroll
    for (int nt = 0; nt < 6; nt++)
#pragma unroll
      for (int f = 0; f < 4; f++) red[wv - 2][nt][f][lane] = acc[nt][f];
  }
  __syncthreads();
  if (wv < 2) {
#pragma unroll
    for (int nt = 0; nt < 6; nt++)
#pragma unroll
      for (int f = 0; f < 4; f++) {
        f32x4 v = red[wv][nt][f][lane];
#pragma unroll
        for (int j = 0; j < 4; j++) acc[nt][f][j] += v[j];
      }
  }
  if (wv == 1) {
#pragma unroll
    for (int nt = 0; nt < 6; nt++)
#pragma unroll
      for (int f = 0; f < 4; f++) red[1][nt][f][lane] = acc[nt][f];
  }
  __syncthreads();
  if (wv == 0) {
    float* op = out + ((size_t)b * 84 * 64 + h) * 64;
#pragma unroll
    for (int nt = 0; nt < 6; nt++)
#pragma unroll
      for (int f = 0; f < 4; f++) {
        f32x4 v = red[1][nt][f][lane];
#pragma unroll
        for (int j = 0; j < 4; j++) acc[nt][f][j] += v[j];
      }
#pragma unroll
    for (int nt = 0; nt < 6; nt++)
#pragma unroll
      for (int j = 0; j < 4; j++) {
        int o = nt * 16 + lg * 4 + j;
        if (o < 84) {
          float bv = bias[o];
#pragma unroll
          for (int f = 0; f < 4; f++)
            op[(size_t)o * 4096 + f * 16 + lrow] = acc[nt][f][j] + bv;
        }
      }
  }
}

// ---- launch -----------------------------------------------------------------
extern "C" void kernel_launch(void* const* d_in, const int* in_sizes, int n_in,
                              void* d_out, int out_size, void* d_ws, size_t ws_size,
                              hipStream_t stream) {
  const float* x   = (const float*)d_in[0];
  const float* dm0 = (const float*)d_in[1];
  const float* dm1 = (const float*)d_in[2];
  const float* w0  = (const float*)d_in[3];
  const float* w1  = (const float*)d_in[4];
  const float* wf  = (const float*)d_in[5];
  const float* bf  = (const float*)d_in[6];
  float* out = (float*)d_out;

  u16* xT = (u16*)d_ws;                                               // 8 MiB
  u16* weffg = (u16*)((char*)d_ws + (size_t)8 * 64 * 64 * 128 * 2);   // 432 KiB

  transpose_k<<<512, 256, 0, stream>>>(x, xT);
  weff_k<<<864, 256, 0, stream>>>(w0, w1, wf, weffg);
  deform_main<<<512, 256, 0, stream>>>(xT, weffg, dm0, dm1, bf, out);
}

// Round 6
// 103.097 us; speedup vs baseline: 2.3560x; 1.0210x over previous
//
#include <hip/hip_runtime.h>
#include <hip/hip_bf16.h>

using u16 = unsigned short;
using u32 = unsigned int;
typedef float f32x4 __attribute__((ext_vector_type(4)));
typedef float f32x2 __attribute__((ext_vector_type(2)));
typedef __bf16 bf16x8 __attribute__((ext_vector_type(8)));

// ---- helpers ----------------------------------------------------------------
static __device__ __forceinline__ float bflo(u32 u) { return __uint_as_float(u << 16); }
static __device__ __forceinline__ float bfhi(u32 u) { return __uint_as_float(u & 0xffff0000u); }

static __device__ __forceinline__ u32 pack2(float a, float b) {
  __hip_bfloat16 ha = __float2bfloat16(a);
  __hip_bfloat16 hb = __float2bfloat16(b);
  u16 ra, rb;
  __builtin_memcpy(&ra, &ha, 2);
  __builtin_memcpy(&rb, &hb, 2);
  return (u32)ra | ((u32)rb << 16);
}

static __device__ __forceinline__ u16 f2bf(float f) {
  u32 u = __float_as_uint(f);
  u32 r = (u + 0x7fffu + ((u >> 16) & 1u)) >> 16;
  return (u16)r;
}

static __device__ __forceinline__ bf16x8 as_bf(uint4 v) {
  bf16x8 r;
  __builtin_memcpy(&r, &v, 16);
  return r;
}

// truncating pack of two blended f32 -> bf16x2, single v_perm_b32
static __device__ __forceinline__ u32 packtrunc(float lo, float hi) {
  return __builtin_amdgcn_perm(__float_as_uint(hi), __float_as_uint(lo), 0x07060302u);
}

static __device__ __forceinline__ f32x2 unpk(u32 u) {
  f32x2 r;
  r.x = bflo(u);
  r.y = bfhi(u);
  return r;
}

// 4-corner bilinear blend of 8 bf16 channels -> bf16x8 fragment (as uint4)
static __device__ __forceinline__ uint4 blend4(uint4 a, uint4 b, uint4 c, uint4 d,
                                               float w00, float w01, float w10, float w11) {
  uint4 r;
#pragma unroll
  for (int j = 0; j < 4; j++) {
    f32x2 v = unpk((&a.x)[j]) * w00;
    v += unpk((&b.x)[j]) * w01;
    v += unpk((&c.x)[j]) * w10;
    v += unpk((&d.x)[j]) * w11;
    (&r.x)[j] = packtrunc(v.x, v.y);
  }
  return r;
}

// ---- kernel 1: x [B,C,H,W] f32 -> xT [B,H,W,C] bf16 -------------------------
__global__ __launch_bounds__(256) void transpose_k(const float* __restrict__ x,
                                                   u16* __restrict__ xT) {
  const int bid = blockIdx.x;
  const int b = bid >> 6, y = bid & 63;
  const int t = threadIdx.x;
  const int cg = t >> 4;
  const int w16 = t & 15;
  const float* xp = x + ((size_t)(b * 128) * 64 + y) * 64;
  u16* op = xT + ((size_t)(b * 64 + y) * 64) * 128;
#pragma unroll
  for (int pass = 0; pass < 4; pass++) {
    int w = pass * 16 + w16;
    u32 rr[4];
#pragma unroll
    for (int jj = 0; jj < 4; jj++) {
      float a = xp[(cg * 8 + 2 * jj) * 4096 + w];
      float c = xp[(cg * 8 + 2 * jj + 1) * 4096 + w];
      rr[jj] = pack2(a, c);
    }
    uint4 r;
    r.x = rr[0]; r.y = rr[1]; r.z = rr[2]; r.w = rr[3];
    *(uint4*)(op + w * 128 + cg * 8) = r;
  }
}

// ---- kernel 2: weff in MFMA-A-fragment layout --------------------------------
// element index = ((ks*6 + nt)*64 + lane)*8 + j
//   n (=o) = nt*16 + (lane&15);  kc = (lane>>4)*8 + j
// ks: br = ks>=36, ksb = ks-36*br, tap = ksb>>2, chunk = ksb&3, c = chunk*32+kc
__global__ __launch_bounds__(256) void weff_k(const float* __restrict__ w0,
                                              const float* __restrict__ w1,
                                              const float* __restrict__ wf,
                                              u16* __restrict__ weffg) {
  const int idx = blockIdx.x * 256 + threadIdx.x;  // 221184 total
  const int j = idx & 7;
  const int l = (idx >> 3) & 63;
  const int rest = idx >> 9;       // ks*6 + nt, 0..431
  const int nt = rest % 6;
  const int ks = rest / 6;
  const int n = nt * 16 + (l & 15);
  const int kc = (l >> 4) * 8 + j;
  const int br = ks >= 36 ? 1 : 0;
  const int ksb = ks - br * 36;
  const int tap = ksb >> 2, chunk = ksb & 3;
  const int c = chunk * 32 + kc;
  float acc = 0.f;
  if (n < 84) {
    const float* w = br ? w1 : w0;
    const float* wfp = wf + n * 168 + br * 84;
    const float* wp = w + c * 9 + tap;   // stride per oc = 128*9 = 1152
#pragma unroll 4
    for (int oc = 0; oc < 84; oc++) acc += wfp[oc] * wp[oc * 1152];
  }
  weffg[idx] = f2bf(acc);
}

// ---- kernel 3: fused deform-sample + GEMM, occupancy-first ------------------
// 1024 blocks = (b:8 -> XCD-pinned) x (h:64) x (half:2). 4 waves = (br:2, cp:2).
// Wave: 32 px x 96 out x K=576, 18 phases (9 taps x 2 chunks of 32 ch).
// Phase: weff(6) | blend qa -> af0,af1 | issue next phase's 8 gathers | 12 MFMA.
// Register budget: acc 48 + q 32 + addr/wt ~20 + misc ~20 ~= 120 <= 128 cap of
// (256,2)  [toolchain law: (256,w) caps VGPR at ~256/w; r3 fit 120 at this cap].
// Residency target: VGPR<=128 -> 4 waves/SIMD; LDS 24KB -> 4 blocks/CU;
// grid 1024 -> 4 blocks/CU => 16 waves/CU (50%) vs r5's ~3 avg.
__global__ __launch_bounds__(256, 2) void deform_main(
    const u16* __restrict__ xT, const u16* __restrict__ weffg,
    const float* __restrict__ dm0, const float* __restrict__ dm1,
    const float* __restrict__ bias, float* __restrict__ out) {
  __shared__ f32x4 red[2][6][2][64];   // 24 KiB

  const int t = threadIdx.x;
  const int wv = t >> 6, lane = t & 63;
  const int br = wv >> 1, cp = wv & 1;
  const int lrow = lane & 15, lg = lane >> 4;
  const int blk = blockIdx.x;
  const int b = blk & 7;
  const int rem = blk >> 3;            // 0..127
  const int h = rem & 63;
  const int half = rem >> 6;
  const int px0 = half * 32;

  const u16* xb = xT + (size_t)b * 524288;
  const float* dmb = (br ? dm1 : dm0) + (size_t)b * 73728 + h * 64 + px0 + lrow;
  const u16* wbase = weffg + (size_t)(br * 36 + cp * 2) * 3072 + lane * 8;
  const int cb = cp * 64 + lg * 8;     // channel base (u16 elems) for this lane

  f32x4 acc[6][2];
#pragma unroll
  for (int i = 0; i < 6; i++)
#pragma unroll
    for (int f = 0; f < 2; f++) acc[i][f] = f32x4{0.f, 0.f, 0.f, 0.f};

  float w00a[2], w01a[2], w10a[2], w11a[2];
  int r0a[2], r1a[2], xo0a[2], xo1a[2];
  float dyN[2], dxN[2];
  uint4 q[8];    // 2 frags x 4 corners in flight (one phase ahead)

  auto tapstate = [&](int f, int ty, int tx, float dy, float dx) {
    float pyf = (float)(h + ty - 1) + dy;
    float pxf = (float)(px0 + f * 16 + lrow + tx - 1) + dx;
    float y0f = floorf(pyf), x0f = floorf(pxf);
    int y0 = (int)y0f, x0 = (int)x0f;
    float wy1 = pyf - y0f, wx1 = pxf - x0f;
    float wy0 = 1.f - wy1, wx0 = 1.f - wx1;
    int y1 = y0 + 1, x1 = x0 + 1;
    wy0 *= ((u32)y0 < 64u) ? 1.f : 0.f;
    wy1 *= ((u32)y1 < 64u) ? 1.f : 0.f;
    wx0 *= ((u32)x0 < 64u) ? 1.f : 0.f;
    wx1 *= ((u32)x1 < 64u) ? 1.f : 0.f;
    w00a[f] = wy0 * wx0; w01a[f] = wy0 * wx1;
    w10a[f] = wy1 * wx0; w11a[f] = wy1 * wx1;
    int y0c = min(63, max(0, y0)), y1c = min(63, max(0, y1));
    int x0c = min(63, max(0, x0)), x1c = min(63, max(0, x1));
    r0a[f] = y0c * 8192 + cb; r1a[f] = y1c * 8192 + cb;
    xo0a[f] = x0c * 128; xo1a[f] = x1c * 128;
  };

  auto issue = [&](int co) {
#pragma unroll
    for (int f = 0; f < 2; f++) {
      const u16* p0 = xb + r0a[f] + co;
      const u16* p1 = xb + r1a[f] + co;
      q[f * 4 + 0] = *(const uint4*)(p0 + xo0a[f]);
      q[f * 4 + 1] = *(const uint4*)(p0 + xo1a[f]);
      q[f * 4 + 2] = *(const uint4*)(p1 + xo0a[f]);
      q[f * 4 + 3] = *(const uint4*)(p1 + xo1a[f]);
    }
  };

  // ---- prologue: tap 0 state, issue phase-0 gathers, prefetch dm(tap1) ----
  {
    float dy0 = dmb[0], dx0 = dmb[4096];
    float dy1 = dmb[16], dx1 = dmb[4096 + 16];
    tapstate(0, 0, 0, dy0, dx0);
    tapstate(1, 0, 0, dy1, dx1);
  }
  issue(0);
  dyN[0] = dmb[2 * 4096]; dxN[0] = dmb[3 * 4096];
  dyN[1] = dmb[2 * 4096 + 16]; dxN[1] = dmb[3 * 4096 + 16];

#pragma unroll 1
  for (int tap = 0; tap < 9; tap++) {
#pragma unroll
    for (int c = 0; c < 2; c++) {
      const u16* wp = wbase + (size_t)(tap * 4 + c) * 3072;
      uint4 wq0 = *(const uint4*)(wp);
      uint4 wq1 = *(const uint4*)(wp + 512);
      uint4 wq2 = *(const uint4*)(wp + 1024);
      uint4 wq3 = *(const uint4*)(wp + 1536);
      uint4 wq4 = *(const uint4*)(wp + 2048);
      uint4 wq5 = *(const uint4*)(wp + 2560);

      // blend current gathers (issued one phase ago)
      uint4 a0 = blend4(q[0], q[1], q[2], q[3], w00a[0], w01a[0], w10a[0], w11a[0]);
      uint4 a1 = blend4(q[4], q[5], q[6], q[7], w00a[1], w01a[1], w10a[1], w11a[1]);

      // issue next phase's gathers (q regs now dead)
      if (c == 0) {
        issue(32);
        if (tap < 8) {
          dyN[0] = dmb[(2 * tap + 2) * 4096]; dxN[0] = dmb[(2 * tap + 3) * 4096];
          dyN[1] = dmb[(2 * tap + 2) * 4096 + 16]; dxN[1] = dmb[(2 * tap + 3) * 4096 + 16];
        }
      } else if (tap < 8) {
        int tn = tap + 1;
        int ty = (tn * 11) >> 5;     // tn/3
        int tx = tn - ty * 3;
        tapstate(0, ty, tx, dyN[0], dxN[0]);
        tapstate(1, ty, tx, dyN[1], dxN[1]);
        issue(0);
      }

      bf16x8 af0 = as_bf(a0), af1 = as_bf(a1);
      __builtin_amdgcn_s_setprio(1);
      acc[0][0] = __builtin_amdgcn_mfma_f32_16x16x32_bf16(as_bf(wq0), af0, acc[0][0], 0, 0, 0);
      acc[1][0] = __builtin_amdgcn_mfma_f32_16x16x32_bf16(as_bf(wq1), af0, acc[1][0], 0, 0, 0);
      acc[2][0] = __builtin_amdgcn_mfma_f32_16x16x32_bf16(as_bf(wq2), af0, acc[2][0], 0, 0, 0);
      acc[3][0] = __builtin_amdgcn_mfma_f32_16x16x32_bf16(as_bf(wq3), af0, acc[3][0], 0, 0, 0);
      acc[4][0] = __builtin_amdgcn_mfma_f32_16x16x32_bf16(as_bf(wq4), af0, acc[4][0], 0, 0, 0);
      acc[5][0] = __builtin_amdgcn_mfma_f32_16x16x32_bf16(as_bf(wq5), af0, acc[5][0], 0, 0, 0);
      acc[0][1] = __builtin_amdgcn_mfma_f32_16x16x32_bf16(as_bf(wq0), af1, acc[0][1], 0, 0, 0);
      acc[1][1] = __builtin_amdgcn_mfma_f32_16x16x32_bf16(as_bf(wq1), af1, acc[1][1], 0, 0, 0);
      acc[2][1] = __builtin_amdgcn_mfma_f32_16x16x32_bf16(as_bf(wq2), af1, acc[2][1], 0, 0, 0);
      acc[3][1] = __builtin_amdgcn_mfma_f32_16x16x32_bf16(as_bf(wq3), af1, acc[3][1], 0, 0, 0);
      acc[4][1] = __builtin_amdgcn_mfma_f32_16x16x32_bf16(as_bf(wq4), af1, acc[4][1], 0, 0, 0);
      acc[5][1] = __builtin_amdgcn_mfma_f32_16x16x32_bf16(as_bf(wq5), af1, acc[5][1], 0, 0, 0);
      __builtin_amdgcn_s_setprio(0);
    }
  }

  // ---- reduce the 4 K-partials across waves, then store ----
  if (wv >= 2) {
#pragma unroll
    for (int nt = 0; nt < 6; nt++)
#pragma unroll
      for (int f = 0; f < 2; f++) red[wv - 2][nt][f][lane] = acc[nt][f];
  }
  __syncthreads();
  if (wv < 2) {
#pragma unroll
    for (int nt = 0; nt < 6; nt++)
#pragma unroll
      for (int f = 0; f < 2; f++) {
        f32x4 v = red[wv][nt][f][lane];
#pragma unroll
        for (int j = 0; j < 4; j++) acc[nt][f][j] += v[j];
      }
  }
  if (wv == 1) {
#pragma unroll
    for (int nt = 0; nt < 6; nt++)
#pragma unroll
      for (int f = 0; f < 2; f++) red[1][nt][f][lane] = acc[nt][f];
  }
  __syncthreads();
  if (wv == 0) {
    float* op = out + ((size_t)b * 84 * 64 + h) * 64 + px0;
#pragma unroll
    for (int nt = 0; nt < 6; nt++)
#pragma unroll
      for (int f = 0; f < 2; f++) {
        f32x4 v = red[1][nt][f][lane];
#pragma unroll
        for (int j = 0; j < 4; j++) acc[nt][f][j] += v[j];
      }
#pragma unroll
    for (int nt = 0; nt < 6; nt++)
#pragma unroll
      for (int j = 0; j < 4; j++) {
        int o = nt * 16 + lg * 4 + j;
        if (o < 84) {
          float bv = bias[o];
#pragma unroll
          for (int f = 0; f < 2; f++)
            op[(size_t)o * 4096 + f * 16 + lrow] = acc[nt][f][j] + bv;
        }
      }
  }
}

// ---- launch -----------------------------------------------------------------
extern "C" void kernel_launch(void* const* d_in, const int* in_sizes, int n_in,
                              void* d_out, int out_size, void* d_ws, size_t ws_size,
                              hipStream_t stream) {
  const float* x   = (const float*)d_in[0];
  const float* dm0 = (const float*)d_in[1];
  const float* dm1 = (const float*)d_in[2];
  const float* w0  = (const float*)d_in[3];
  const float* w1  = (const float*)d_in[4];
  const float* wf  = (const float*)d_in[5];
  const float* bf  = (const float*)d_in[6];
  float* out = (float*)d_out;

  u16* xT = (u16*)d_ws;                                               // 8 MiB
  u16* weffg = (u16*)((char*)d_ws + (size_t)8 * 64 * 64 * 128 * 2);   // 432 KiB

  transpose_k<<<512, 256, 0, stream>>>(x, xT);
  weff_k<<<864, 256, 0, stream>>>(w0, w1, wf, weffg);
  deform_main<<<1024, 256, 0, stream>>>(xT, weffg, dm0, dm1, bf, out);
}